// Round 2
// baseline (11285.953 us; speedup 1.0000x reference)
//
#include <hip/hip_runtime.h>
#include <stdint.h>

// SkipGRU: T=384, B=48, C=H=256, L=2.
// R2: rec_layer uses 4 WGs per batch element (grid 192, block 512).
// Each WG owns 64 h-columns; per-lane W_hh fragment = 24 float4 = 96 VGPRs
// (R1's 48-f4 version spilled: VGPR_Count=124 < needed 192+ under the 256 cap).
// Non-skip step: matvec (regs x LDS-h) -> wave butterfly -> 2 barriers +
// 4-way flag handshake through agent-scope atomics (partners are blocks
// b, b+48, b+96, b+144 -> same XCD under round-robin, but correctness does
// not depend on placement). Skip steps (bu==0, h provably unchanged): just an
// output store, no barriers.

#define T_STEPS 384

__device__ __forceinline__ float sigm_(float x) { return 1.f / (1.f + __expf(-x)); }
__device__ __forceinline__ float tanh_(float x) {
    float ax = fabsf(x);
    float e  = __expf(-2.f * ax);
    float r  = (1.f - e) / (1.f + e);
    return copysignf(r, x);
}

// ---------------------------------------------------------------------------
// GEMM: O[m][n] = sum_k X[m][k] * W[n][k] + B[n];  M=18432, N=768, K=256.
// grid (12, 144), block 256. Tile 128(M) x 64(N), K-chunks of 32 staged in LDS.
// (unchanged from R1 — ~150 us each, not the bottleneck this round)
// ---------------------------------------------------------------------------
__global__ __launch_bounds__(256, 2) void gemm_nt(const float* __restrict__ X,
                                                  const float* __restrict__ W,
                                                  const float* __restrict__ B,
                                                  float* __restrict__ O)
{
    __shared__ float As[32 * 140];
    __shared__ float Bs[32 * 68];

    const int tid = threadIdx.x;
    const int tx  = tid & 15;
    const int ty  = tid >> 4;
    const int n0  = blockIdx.x * 64;
    const int m0  = blockIdx.y * 128;

    float acc[8][4];
#pragma unroll
    for (int i = 0; i < 8; ++i)
#pragma unroll
        for (int j = 0; j < 4; ++j) acc[i][j] = 0.f;

    const float4 bias4 = *reinterpret_cast<const float4*>(B + n0 + tx * 4);

    for (int kc = 0; kc < 8; ++kc) {
        const int k0 = kc * 32;
        float4 a[4], bb[2];
#pragma unroll
        for (int j = 0; j < 4; ++j) {
            int f = tid + 256 * j, r = f >> 3, cq = f & 7;
            a[j] = *reinterpret_cast<const float4*>(X + (size_t)(m0 + r) * 256 + k0 + cq * 4);
        }
#pragma unroll
        for (int j = 0; j < 2; ++j) {
            int f = tid + 256 * j, r = f >> 3, cq = f & 7;
            bb[j] = *reinterpret_cast<const float4*>(W + (size_t)(n0 + r) * 256 + k0 + cq * 4);
        }
        __syncthreads();
#pragma unroll
        for (int j = 0; j < 4; ++j) {
            int f = tid + 256 * j, r = f >> 3, cq = f & 7;
            As[(cq * 4 + 0) * 140 + r] = a[j].x;
            As[(cq * 4 + 1) * 140 + r] = a[j].y;
            As[(cq * 4 + 2) * 140 + r] = a[j].z;
            As[(cq * 4 + 3) * 140 + r] = a[j].w;
        }
#pragma unroll
        for (int j = 0; j < 2; ++j) {
            int f = tid + 256 * j, r = f >> 3, cq = f & 7;
            Bs[(cq * 4 + 0) * 68 + r] = bb[j].x;
            Bs[(cq * 4 + 1) * 68 + r] = bb[j].y;
            Bs[(cq * 4 + 2) * 68 + r] = bb[j].z;
            Bs[(cq * 4 + 3) * 68 + r] = bb[j].w;
        }
        __syncthreads();
#pragma unroll 8
        for (int kk = 0; kk < 32; ++kk) {
            float4 av0 = *reinterpret_cast<const float4*>(As + kk * 140 + ty * 8);
            float4 av1 = *reinterpret_cast<const float4*>(As + kk * 140 + ty * 8 + 4);
            float4 bv  = *reinterpret_cast<const float4*>(Bs + kk * 68 + tx * 4);
            float am[8] = {av0.x, av0.y, av0.z, av0.w, av1.x, av1.y, av1.z, av1.w};
            float bn[4] = {bv.x, bv.y, bv.z, bv.w};
#pragma unroll
            for (int i = 0; i < 8; ++i)
#pragma unroll
                for (int j = 0; j < 4; ++j) acc[i][j] = fmaf(am[i], bn[j], acc[i][j]);
        }
    }
#pragma unroll
    for (int i = 0; i < 8; ++i) {
        int row = m0 + ty * 8 + i;
        float4 o;
        o.x = acc[i][0] + bias4.x;
        o.y = acc[i][1] + bias4.y;
        o.z = acc[i][2] + bias4.z;
        o.w = acc[i][3] + bias4.w;
        *reinterpret_cast<float4*>(O + (size_t)row * 768 + n0 + tx * 4) = o;
    }
}

// ---------------------------------------------------------------------------
// Recurrence. grid = 192 (p = blk/48 in {0..3}, b = blk%48), block 512.
// WG p owns h-columns [p*64, p*64+64). Wave w (0..7): column c = p*64+w*8+g,
// g = lane&7; k-slice s = lane>>3 covers k in [s*32, s*32+32).
// Per-lane W: 3 gate rows x 8 float4 = 24 f4 = 96 VGPRs (no spill).
// hbuf: 8 bank-shifted copies of h (stride 260); lane reads copy s at word
// offset s*292+4i -> bank (4s+4i)%32, conflict-free b128 reads.
// ---------------------------------------------------------------------------
__global__ __launch_bounds__(512, 2) void rec_layer(
    const float* __restrict__ GI, float* __restrict__ Yout,
    const float* __restrict__ whh, const float* __restrict__ bhh,
    const float* __restrict__ lwl, const float* __restrict__ lbl,
    const float* __restrict__ hid,
    float* XH, float* PD, int* FLG,
    float* __restrict__ hsout, float* __restrict__ tuout)
{
    __shared__ float hbuf[8 * 260];
    __shared__ float nhslot[64];
    __shared__ float pdw[8];
    __shared__ float pdx[4];

    const int tid  = threadIdx.x;
    const int lane = tid & 63;
    const int w    = tid >> 6;
    const int g    = lane & 7;
    const int s    = lane >> 3;          // k-slice 0..7
    const int b    = blockIdx.x % 48;
    const int p    = blockIdx.x / 48;    // quarter 0..3
    const int c    = p * 64 + w * 8 + g; // owned global column

    // W_hh fragments -> registers
    float4 Wr[8], Wz[8], Wn[8];
    {
        const float4* wr4 = reinterpret_cast<const float4*>(whh + (size_t)c * 256 + s * 32);
        const float4* wz4 = reinterpret_cast<const float4*>(whh + (size_t)(256 + c) * 256 + s * 32);
        const float4* wn4 = reinterpret_cast<const float4*>(whh + (size_t)(512 + c) * 256 + s * 32);
#pragma unroll
        for (int i = 0; i < 8; ++i) { Wr[i] = wr4[i]; Wz[i] = wz4[i]; Wn[i] = wn4[i]; }
    }

    const float bhr = bhh[c], bhz = bhh[256 + c], bhn = bhh[512 + c];
    const float lwc = lwl[c];
    const float lbv = lbl[0];

    if (tid < 256) {
        float v = hid[tid];
#pragma unroll
        for (int j = 0; j < 8; ++j) hbuf[j * 260 + tid] = v;
    }
    float hreg = hid[c];   // current h[c], authoritative on s==0 lanes
    __syncthreads();

    float u = 1.f, d = 0.f;
    bool  skip = false;
    int   ns = 0;          // non-skip step counter; parity = ns&1

    float* XHb = XH + b * 512;   // [parity][256]
    float* PDb = PD + b * 8;     // [parity][4]
    int*   FLGb = FLG + b * 4;

    for (int t = 0; t < T_STEPS; ++t) {
        const size_t yrow = ((size_t)t * 48 + b) * 256;

        if (skip) {
            // skip => u<0.5 => bu=rint(u)=0 => new_h = h, new_d = d,
            // new_u = clip(u+d,0,1). No shared state changes at all.
            if (s == 0) {
                Yout[yrow + c] = hreg;
                if (t == T_STEPS - 1) hsout[b * 256 + c] = hreg;
            }
            if (p == 0 && tid == 0) tuout[b * 768 + t] = 0.f;
            u = fminf(fmaxf(u + d, 0.f), 1.f);
            skip = (u < 0.5f);
            continue;
        }

        const float bu = rintf(u);  // == 1 except measure-zero u==0.5 exact
        float gir = 0.f, giz = 0.f, gin = 0.f;
        if (s == 0) {
            const size_t gbase = ((size_t)t * 48 + b) * 768 + c;
            gir = GI[gbase]; giz = GI[gbase + 256]; gin = GI[gbase + 512];
        }

        // matvec: ar/az/an = W[c,:] . h  over k-slice s
        float ar = 0.f, az = 0.f, an = 0.f;
        const float4* h4 = reinterpret_cast<const float4*>(hbuf + s * 292); // s*260 + s*32
#pragma unroll
        for (int i = 0; i < 8; ++i) {
            float4 hv = h4[i];
            ar = fmaf(Wr[i].x, hv.x, ar); ar = fmaf(Wr[i].y, hv.y, ar);
            ar = fmaf(Wr[i].z, hv.z, ar); ar = fmaf(Wr[i].w, hv.w, ar);
            az = fmaf(Wz[i].x, hv.x, az); az = fmaf(Wz[i].y, hv.y, az);
            az = fmaf(Wz[i].z, hv.z, az); az = fmaf(Wz[i].w, hv.w, az);
            an = fmaf(Wn[i].x, hv.x, an); an = fmaf(Wn[i].y, hv.y, an);
            an = fmaf(Wn[i].z, hv.z, an); an = fmaf(Wn[i].w, hv.w, an);
        }
        ar += __shfl_xor(ar, 8); ar += __shfl_xor(ar, 16); ar += __shfl_xor(ar, 32);
        az += __shfl_xor(az, 8); az += __shfl_xor(az, 16); az += __shfl_xor(az, 32);
        an += __shfl_xor(an, 8); an += __shfl_xor(an, 16); an += __shfl_xor(an, 32);

        float pdv = 0.f;
        if (s == 0) {
            float rr = sigm_(gir + ar + bhr);
            float zz = sigm_(giz + az + bhz);
            float nn = tanh_(gin + rr * (an + bhn));
            float nh = ((1.f - zz) * nn + zz * hreg) * bu;
            hreg = nh;
            Yout[yrow + c] = nh;
            if (t == T_STEPS - 1) hsout[b * 256 + c] = nh;
            __hip_atomic_store(XHb + (ns & 1) * 256 + c, nh,
                               __ATOMIC_RELAXED, __HIP_MEMORY_SCOPE_AGENT);
            nhslot[w * 8 + g] = nh;
            pdv = nh * lwc;
        }
        // sum pd over the 8 s==0 lanes (lanes 0..7); others contribute 0
        pdv += __shfl_xor(pdv, 1); pdv += __shfl_xor(pdv, 2); pdv += __shfl_xor(pdv, 4);
        if (lane == 0) pdw[w] = pdv;
        if (p == 0 && tid == 0) tuout[b * 768 + t] = bu;

        __syncthreads();  // A: matvec hbuf reads done; nhslot/pdw ready; XH stores drained

        if (tid == 0) {
            float ownpd = ((pdw[0] + pdw[1]) + (pdw[2] + pdw[3]))
                        + ((pdw[4] + pdw[5]) + (pdw[6] + pdw[7]));
            __hip_atomic_store(PDb + (ns & 1) * 4 + p, ownpd,
                               __ATOMIC_RELAXED, __HIP_MEMORY_SCOPE_AGENT);
            __hip_atomic_store(FLGb + p, ns + 1,
                               __ATOMIC_RELEASE, __HIP_MEMORY_SCOPE_AGENT);
            pdx[p] = ownpd;
        }
        if (w == 0) {
            // own 64 columns -> all 8 hbuf copies
            float v = nhslot[lane];
#pragma unroll
            for (int j = 0; j < 8; ++j) hbuf[j * 260 + p * 64 + lane] = v;
        } else if (w < 4) {
            // wave w fetches partner (p+w)&3's slice
            const int q = (p + w) & 3;
            const int target = ns + 1;
            while (__hip_atomic_load(FLGb + q, __ATOMIC_ACQUIRE,
                                     __HIP_MEMORY_SCOPE_AGENT) < target) { }
            float v = __hip_atomic_load(XHb + (ns & 1) * 256 + q * 64 + lane,
                                        __ATOMIC_RELAXED, __HIP_MEMORY_SCOPE_AGENT);
#pragma unroll
            for (int j = 0; j < 8; ++j) hbuf[j * 260 + q * 64 + lane] = v;
            if (lane == 0)
                pdx[q] = __hip_atomic_load(PDb + (ns & 1) * 4 + q,
                                           __ATOMIC_RELAXED, __HIP_MEMORY_SCOPE_AGENT);
        }

        __syncthreads();  // B: full h in hbuf, all four pdx slots staged

        float dns = sigm_(((pdx[0] + pdx[1]) + (pdx[2] + pdx[3])) + lbv);
        u = dns * bu;
        d = dns;
        skip = (u < 0.5f);
        ns++;
    }
}

// ---------------------------------------------------------------------------
extern "C" void kernel_launch(void* const* d_in, const int* in_sizes, int n_in,
                              void* d_out, int out_size, void* d_ws, size_t ws_size,
                              hipStream_t stream)
{
    const float* x   = (const float*)d_in[0];  // (384,48,256)
    const float* hid = (const float*)d_in[1];  // (2,1,256)
    const float* wih = (const float*)d_in[2];  // (2,768,256)
    const float* whh = (const float*)d_in[3];  // (2,768,256)
    const float* bih = (const float*)d_in[4];  // (2,768)
    const float* bhh = (const float*)d_in[5];  // (2,768)
    const float* lw  = (const float*)d_in[6];  // (2,1,256)
    const float* lb  = (const float*)d_in[7];  // (2,1)
    float* out = (float*)d_out;

    float* ws   = (float*)d_ws;
    float* GI   = ws;                               // 18432*768
    float* Y0   = GI + (size_t)18432 * 768;         // 18432*256
    float* XH0  = Y0 + (size_t)18432 * 256;         // 48*2*256
    float* XH1  = XH0 + 48 * 512;
    float* PD0  = XH1 + 48 * 512;                   // 48*2*4
    float* PD1  = PD0 + 48 * 8;
    int*   FLG0 = (int*)(PD1 + 48 * 8);             // 48*4 ints per layer
    int*   FLG1 = FLG0 + 48 * 4;

    float* OUTy = out;                              // (384,48,256)
    float* HS   = out + (size_t)18432 * 256;        // (2,48,256)
    float* TU   = HS + 2 * 48 * 256;                // (48, 768)

    // flags must start at 0 regardless of workspace poison
    hipMemsetAsync(FLG0, 0, 2 * 48 * 4 * sizeof(int), stream);

    dim3 ggrid(12, 144), gblk(256);
    gemm_nt<<<ggrid, gblk, 0, stream>>>(x, wih, bih, GI);
    rec_layer<<<192, 512, 0, stream>>>(GI, Y0, whh, bhh, lw, lb, hid,
                                       XH0, PD0, FLG0, HS, TU);
    gemm_nt<<<ggrid, gblk, 0, stream>>>(Y0, wih + 196608, bih + 768, GI);
    rec_layer<<<192, 512, 0, stream>>>(GI, OUTy, whh + 196608, bhh + 768,
                                       lw + 256, lb + 1, hid + 256,
                                       XH1, PD1, FLG1, HS + 12288, TU + 384);
}

// Round 3
// 10862.718 us; speedup vs baseline: 1.0390x; 1.0390x over previous
//
#include <hip/hip_runtime.h>
#include <stdint.h>

// SkipGRU: T=384, B=48, C=H=256, L=2.
// R3: rec_layer = 4 WGs per batch element, 256 threads each, launch_bounds(256,1)
// -> 1 wave/SIMD -> 512-VGPR cap so the 192-VGPR W_hh fragment stays resident
// (R1/R2 failed here: allocator spilled/sank W under the 256 cap).
// Partners {b, b+48, b+96, b+144} land on one XCD under round-robin dispatch.
// Spin-waits back off with s_sleep (R2's empty agent-scope spin livelocked).
// Skip steps (bu==0 -> h unchanged): no barriers, no traffic.

#define T_STEPS 384

__device__ __forceinline__ float sigm_(float x) { return 1.f / (1.f + __expf(-x)); }
__device__ __forceinline__ float tanh_(float x) {
    float ax = fabsf(x);
    float e  = __expf(-2.f * ax);
    float r  = (1.f - e) / (1.f + e);
    return copysignf(r, x);
}

// ---------------------------------------------------------------------------
// GEMM: O[m][n] = sum_k X[m][k] * W[n][k] + B[n];  M=18432, N=768, K=256.
// grid (12, 144), block 256. Tile 128(M) x 64(N), K-chunks of 32 in LDS.
// (unchanged; ~150 us each, not the current bottleneck)
// ---------------------------------------------------------------------------
__global__ __launch_bounds__(256, 2) void gemm_nt(const float* __restrict__ X,
                                                  const float* __restrict__ W,
                                                  const float* __restrict__ B,
                                                  float* __restrict__ O)
{
    __shared__ float As[32 * 140];
    __shared__ float Bs[32 * 68];

    const int tid = threadIdx.x;
    const int tx  = tid & 15;
    const int ty  = tid >> 4;
    const int n0  = blockIdx.x * 64;
    const int m0  = blockIdx.y * 128;

    float acc[8][4];
#pragma unroll
    for (int i = 0; i < 8; ++i)
#pragma unroll
        for (int j = 0; j < 4; ++j) acc[i][j] = 0.f;

    const float4 bias4 = *reinterpret_cast<const float4*>(B + n0 + tx * 4);

    for (int kc = 0; kc < 8; ++kc) {
        const int k0 = kc * 32;
        float4 a[4], bb[2];
#pragma unroll
        for (int j = 0; j < 4; ++j) {
            int f = tid + 256 * j, r = f >> 3, cq = f & 7;
            a[j] = *reinterpret_cast<const float4*>(X + (size_t)(m0 + r) * 256 + k0 + cq * 4);
        }
#pragma unroll
        for (int j = 0; j < 2; ++j) {
            int f = tid + 256 * j, r = f >> 3, cq = f & 7;
            bb[j] = *reinterpret_cast<const float4*>(W + (size_t)(n0 + r) * 256 + k0 + cq * 4);
        }
        __syncthreads();
#pragma unroll
        for (int j = 0; j < 4; ++j) {
            int f = tid + 256 * j, r = f >> 3, cq = f & 7;
            As[(cq * 4 + 0) * 140 + r] = a[j].x;
            As[(cq * 4 + 1) * 140 + r] = a[j].y;
            As[(cq * 4 + 2) * 140 + r] = a[j].z;
            As[(cq * 4 + 3) * 140 + r] = a[j].w;
        }
#pragma unroll
        for (int j = 0; j < 2; ++j) {
            int f = tid + 256 * j, r = f >> 3, cq = f & 7;
            Bs[(cq * 4 + 0) * 68 + r] = bb[j].x;
            Bs[(cq * 4 + 1) * 68 + r] = bb[j].y;
            Bs[(cq * 4 + 2) * 68 + r] = bb[j].z;
            Bs[(cq * 4 + 3) * 68 + r] = bb[j].w;
        }
        __syncthreads();
#pragma unroll 8
        for (int kk = 0; kk < 32; ++kk) {
            float4 av0 = *reinterpret_cast<const float4*>(As + kk * 140 + ty * 8);
            float4 av1 = *reinterpret_cast<const float4*>(As + kk * 140 + ty * 8 + 4);
            float4 bv  = *reinterpret_cast<const float4*>(Bs + kk * 68 + tx * 4);
            float am[8] = {av0.x, av0.y, av0.z, av0.w, av1.x, av1.y, av1.z, av1.w};
            float bn[4] = {bv.x, bv.y, bv.z, bv.w};
#pragma unroll
            for (int i = 0; i < 8; ++i)
#pragma unroll
                for (int j = 0; j < 4; ++j) acc[i][j] = fmaf(am[i], bn[j], acc[i][j]);
        }
    }
#pragma unroll
    for (int i = 0; i < 8; ++i) {
        int row = m0 + ty * 8 + i;
        float4 o;
        o.x = acc[i][0] + bias4.x;
        o.y = acc[i][1] + bias4.y;
        o.z = acc[i][2] + bias4.z;
        o.w = acc[i][3] + bias4.w;
        *reinterpret_cast<float4*>(O + (size_t)row * 768 + n0 + tx * 4) = o;
    }
}

// ---------------------------------------------------------------------------
// Recurrence. grid = 192 (p = blk/48 in {0..3}, b = blk%48), block 256.
// WG p owns h-columns [p*64, p*64+64). Wave w (0..3): column c = p*64+w*16+g,
// g = lane&15; k-slice s = lane>>4 covers k in [s*64, s*64+64).
// Per-lane W: 3 gates x 16 float4 = 192 VGPRs; cap is 512 (1 wave/SIMD).
// hbuf: 4 bank-shifted copies of h (stride 260). Matvec read at word
// s*324 + 4i -> banks (4s+4i)%32: the 4 k-slices hit disjoint bank quads,
// 16 lanes/slice broadcast -> conflict-free ds_read_b128.
// ---------------------------------------------------------------------------
__global__ __launch_bounds__(256, 1) void rec_layer(
    const float* __restrict__ GI, float* __restrict__ Yout,
    const float* __restrict__ whh, const float* __restrict__ bhh,
    const float* __restrict__ lwl, const float* __restrict__ lbl,
    const float* __restrict__ hid,
    float* XH, float* PD, int* FLG,
    float* __restrict__ hsout, float* __restrict__ tuout)
{
    __shared__ float hbuf[1040];   // 4 copies x 260
    __shared__ float nhslot[64];
    __shared__ float pdw[4];
    __shared__ float pdx[4];

    const int tid  = threadIdx.x;
    const int lane = tid & 63;
    const int w    = tid >> 6;           // wave 0..3
    const int g    = lane & 15;
    const int s    = lane >> 4;          // k-slice 0..3
    const int b    = blockIdx.x % 48;
    const int p    = blockIdx.x / 48;    // quarter 0..3; partners same XCD
    const int c    = p * 64 + w * 16 + g;

    // W_hh fragments -> registers (192 VGPRs/lane; headroom to 512)
    float4 Wr[16], Wz[16], Wn[16];
    {
        const float4* wr4 = reinterpret_cast<const float4*>(whh + (size_t)c * 256 + s * 64);
        const float4* wz4 = reinterpret_cast<const float4*>(whh + (size_t)(256 + c) * 256 + s * 64);
        const float4* wn4 = reinterpret_cast<const float4*>(whh + (size_t)(512 + c) * 256 + s * 64);
#pragma unroll
        for (int i = 0; i < 16; ++i) { Wr[i] = wr4[i]; Wz[i] = wz4[i]; Wn[i] = wn4[i]; }
    }

    const float bhr = bhh[c], bhz = bhh[256 + c], bhn = bhh[512 + c];
    const float lwc = lwl[c];
    const float lbv = lbl[0];

    {
        float v = hid[tid];
#pragma unroll
        for (int j = 0; j < 4; ++j) hbuf[j * 260 + tid] = v;
    }
    float hreg = hid[c];   // authoritative on s==0 lanes
    __syncthreads();

    float u = 1.f, d = 0.f;
    bool  skip = false;
    int   ns = 0;          // non-skip step counter; parity = ns&1

    float* XHb  = XH + b * 512;   // [parity][256]
    float* PDb  = PD + b * 8;     // [parity][4]
    int*   FLGb = FLG + b * 4;

    for (int t = 0; t < T_STEPS; ++t) {
        const size_t yrow = ((size_t)t * 48 + b) * 256;

        if (skip) {
            // u<0.5 -> bu=0 -> h,d unchanged; u = clip(u+d,0,1). No sync.
            if (s == 0) {
                Yout[yrow + c] = hreg;
                if (t == T_STEPS - 1) hsout[b * 256 + c] = hreg;
            }
            if (p == 0 && tid == 0) tuout[b * 768 + t] = 0.f;
            u = fminf(fmaxf(u + d, 0.f), 1.f);
            skip = (u < 0.5f);
            continue;
        }

        const float bu = rintf(u);  // RNE, matches jnp.round
        float gir = 0.f, giz = 0.f, gin = 0.f;
        if (s == 0) {
            const size_t gbase = ((size_t)t * 48 + b) * 768 + c;
            gir = GI[gbase]; giz = GI[gbase + 256]; gin = GI[gbase + 512];
        }

        // matvec over k-slice s: 16 float4 of h, 192 FMAs
        float ar = 0.f, az = 0.f, an = 0.f;
        const float4* h4 = reinterpret_cast<const float4*>(hbuf + s * 324); // s*260 + s*64
#pragma unroll
        for (int i = 0; i < 16; ++i) {
            float4 hv = h4[i];
            ar = fmaf(Wr[i].x, hv.x, ar); ar = fmaf(Wr[i].y, hv.y, ar);
            ar = fmaf(Wr[i].z, hv.z, ar); ar = fmaf(Wr[i].w, hv.w, ar);
            az = fmaf(Wz[i].x, hv.x, az); az = fmaf(Wz[i].y, hv.y, az);
            az = fmaf(Wz[i].z, hv.z, az); az = fmaf(Wz[i].w, hv.w, az);
            an = fmaf(Wn[i].x, hv.x, an); an = fmaf(Wn[i].y, hv.y, an);
            an = fmaf(Wn[i].z, hv.z, an); an = fmaf(Wn[i].w, hv.w, an);
        }
        ar += __shfl_xor(ar, 16); ar += __shfl_xor(ar, 32);
        az += __shfl_xor(az, 16); az += __shfl_xor(az, 32);
        an += __shfl_xor(an, 16); an += __shfl_xor(an, 32);

        float pdv = 0.f;
        if (s == 0) {
            float rr = sigm_(gir + ar + bhr);
            float zz = sigm_(giz + az + bhz);
            float nn = tanh_(gin + rr * (an + bhn));
            float nh = ((1.f - zz) * nn + zz * hreg) * bu;
            hreg = nh;
            Yout[yrow + c] = nh;
            if (t == T_STEPS - 1) hsout[b * 256 + c] = nh;
            __hip_atomic_store(XHb + (ns & 1) * 256 + c, nh,
                               __ATOMIC_RELAXED, __HIP_MEMORY_SCOPE_AGENT);
            nhslot[w * 16 + g] = nh;
            pdv = nh * lwc;
        }
        // sum over the 16 s==0 lanes (others are 0); offsets <16 stay in-group
        pdv += __shfl_xor(pdv, 1); pdv += __shfl_xor(pdv, 2);
        pdv += __shfl_xor(pdv, 4); pdv += __shfl_xor(pdv, 8);
        if (lane == 0) pdw[w] = pdv;
        if (p == 0 && tid == 0) tuout[b * 768 + t] = bu;

        __syncthreads();  // A: hbuf reads done; nhslot/pdw ready; XH stores drained

        if (tid == 0) {
            float ownpd = (pdw[0] + pdw[1]) + (pdw[2] + pdw[3]);
            __hip_atomic_store(PDb + (ns & 1) * 4 + p, ownpd,
                               __ATOMIC_RELAXED, __HIP_MEMORY_SCOPE_AGENT);
            __hip_atomic_store(FLGb + p, ns + 1,
                               __ATOMIC_RELEASE, __HIP_MEMORY_SCOPE_AGENT);
            pdx[p] = ownpd;
        }
        if (w == 0) {
            // own 64 columns -> all 4 hbuf copies
            float v = nhslot[lane];
#pragma unroll
            for (int j = 0; j < 4; ++j) hbuf[j * 260 + p * 64 + lane] = v;
        } else {
            // wave w fetches partner (p+w)&3's 64-column slice
            const int q = (p + w) & 3;
            const int target = ns + 1;
            while (__hip_atomic_load(FLGb + q, __ATOMIC_ACQUIRE,
                                     __HIP_MEMORY_SCOPE_AGENT) < target) {
                __builtin_amdgcn_s_sleep(2);   // backoff: R2's empty spin livelocked
            }
            float v = __hip_atomic_load(XHb + (ns & 1) * 256 + q * 64 + lane,
                                        __ATOMIC_RELAXED, __HIP_MEMORY_SCOPE_AGENT);
#pragma unroll
            for (int j = 0; j < 4; ++j) hbuf[j * 260 + q * 64 + lane] = v;
            if (lane == 0)
                pdx[q] = __hip_atomic_load(PDb + (ns & 1) * 4 + q,
                                           __ATOMIC_RELAXED, __HIP_MEMORY_SCOPE_AGENT);
        }

        __syncthreads();  // B: full h in hbuf, all four pdx slots staged

        float dns = sigm_(((pdx[0] + pdx[1]) + (pdx[2] + pdx[3])) + lbv);
        u = dns * bu;
        d = dns;
        skip = (u < 0.5f);
        ns++;
    }
}

// ---------------------------------------------------------------------------
extern "C" void kernel_launch(void* const* d_in, const int* in_sizes, int n_in,
                              void* d_out, int out_size, void* d_ws, size_t ws_size,
                              hipStream_t stream)
{
    const float* x   = (const float*)d_in[0];  // (384,48,256)
    const float* hid = (const float*)d_in[1];  // (2,1,256)
    const float* wih = (const float*)d_in[2];  // (2,768,256)
    const float* whh = (const float*)d_in[3];  // (2,768,256)
    const float* bih = (const float*)d_in[4];  // (2,768)
    const float* bhh = (const float*)d_in[5];  // (2,768)
    const float* lw  = (const float*)d_in[6];  // (2,1,256)
    const float* lb  = (const float*)d_in[7];  // (2,1)
    float* out = (float*)d_out;

    float* ws   = (float*)d_ws;
    float* GI   = ws;                               // 18432*768
    float* Y0   = GI + (size_t)18432 * 768;         // 18432*256
    float* XH0  = Y0 + (size_t)18432 * 256;         // 48*2*256
    float* XH1  = XH0 + 48 * 512;
    float* PD0  = XH1 + 48 * 512;                   // 48*2*4
    float* PD1  = PD0 + 48 * 8;
    int*   FLG0 = (int*)(PD1 + 48 * 8);             // 48*4 ints per layer
    int*   FLG1 = FLG0 + 48 * 4;

    float* OUTy = out;                              // (384,48,256)
    float* HS   = out + (size_t)18432 * 256;        // (2,48,256)
    float* TU   = HS + 2 * 48 * 256;                // (48, 768)

    // flags must start at 0 regardless of workspace poison
    hipMemsetAsync(FLG0, 0, 2 * 48 * 4 * sizeof(int), stream);

    dim3 ggrid(12, 144), gblk(256);
    gemm_nt<<<ggrid, gblk, 0, stream>>>(x, wih, bih, GI);
    rec_layer<<<192, 256, 0, stream>>>(GI, Y0, whh, bhh, lw, lb, hid,
                                       XH0, PD0, FLG0, HS, TU);
    gemm_nt<<<ggrid, gblk, 0, stream>>>(Y0, wih + 196608, bih + 768, GI);
    rec_layer<<<192, 256, 0, stream>>>(GI, OUTy, whh + 196608, bhh + 768,
                                       lw + 256, lb + 1, hid + 256,
                                       XH1, PD1, FLG1, HS + 12288, TU + 384);
}

// Round 4
// 5074.143 us; speedup vs baseline: 2.2242x; 2.1408x over previous
//
#include <hip/hip_runtime.h>
#include <stdint.h>

// SkipGRU: T=384, B=48, C=H=256, L=2.
// R4: rec_layer = ONE workgroup per batch element (grid 48, block 768 = 12 waves).
// No cross-WG sync at all (R2/R3's agent-scope handshake was the bottleneck and
// livelock source). W_hh (786 KB) is NOT held in registers (R1-R3: compiler
// refuses residency) -- it is streamed from L2 every step, shared by all WGs
// on an XCD. Wave w owns rows [w*64, w*64+64); per iter it does 4 rows:
// quad q = lane>>4 -> row w*64+it*4+q, sub s = lane&15 -> k-chunk [s*16+..].
// Coalesced: per load instr, 16 lanes cover 256 contiguous bytes of one row.
// h (256 floats) lives in LDS; 4 ds_read_b128/lane/step (2-way alias = free).
// 2 barriers per non-skip step; skip steps (bu=0 -> h unchanged) are barrier-free.

#define T_STEPS 384

__device__ __forceinline__ float sigm_(float x) { return 1.f / (1.f + __expf(-x)); }
__device__ __forceinline__ float tanh_(float x) {
    float ax = fabsf(x);
    float e  = __expf(-2.f * ax);
    float r  = (1.f - e) / (1.f + e);
    return copysignf(r, x);
}

// ---------------------------------------------------------------------------
// GEMM: O[m][n] = sum_k X[m][k] * W[n][k] + B[n];  M=18432, N=768, K=256.
// grid (12, 144), block 256. Tile 128(M) x 64(N), K-chunks of 32 in LDS.
// (unchanged; not the bottleneck)
// ---------------------------------------------------------------------------
__global__ __launch_bounds__(256, 2) void gemm_nt(const float* __restrict__ X,
                                                  const float* __restrict__ W,
                                                  const float* __restrict__ B,
                                                  float* __restrict__ O)
{
    __shared__ float As[32 * 140];
    __shared__ float Bs[32 * 68];

    const int tid = threadIdx.x;
    const int tx  = tid & 15;
    const int ty  = tid >> 4;
    const int n0  = blockIdx.x * 64;
    const int m0  = blockIdx.y * 128;

    float acc[8][4];
#pragma unroll
    for (int i = 0; i < 8; ++i)
#pragma unroll
        for (int j = 0; j < 4; ++j) acc[i][j] = 0.f;

    const float4 bias4 = *reinterpret_cast<const float4*>(B + n0 + tx * 4);

    for (int kc = 0; kc < 8; ++kc) {
        const int k0 = kc * 32;
        float4 a[4], bb[2];
#pragma unroll
        for (int j = 0; j < 4; ++j) {
            int f = tid + 256 * j, r = f >> 3, cq = f & 7;
            a[j] = *reinterpret_cast<const float4*>(X + (size_t)(m0 + r) * 256 + k0 + cq * 4);
        }
#pragma unroll
        for (int j = 0; j < 2; ++j) {
            int f = tid + 256 * j, r = f >> 3, cq = f & 7;
            bb[j] = *reinterpret_cast<const float4*>(W + (size_t)(n0 + r) * 256 + k0 + cq * 4);
        }
        __syncthreads();
#pragma unroll
        for (int j = 0; j < 4; ++j) {
            int f = tid + 256 * j, r = f >> 3, cq = f & 7;
            As[(cq * 4 + 0) * 140 + r] = a[j].x;
            As[(cq * 4 + 1) * 140 + r] = a[j].y;
            As[(cq * 4 + 2) * 140 + r] = a[j].z;
            As[(cq * 4 + 3) * 140 + r] = a[j].w;
        }
#pragma unroll
        for (int j = 0; j < 2; ++j) {
            int f = tid + 256 * j, r = f >> 3, cq = f & 7;
            Bs[(cq * 4 + 0) * 68 + r] = bb[j].x;
            Bs[(cq * 4 + 1) * 68 + r] = bb[j].y;
            Bs[(cq * 4 + 2) * 68 + r] = bb[j].z;
            Bs[(cq * 4 + 3) * 68 + r] = bb[j].w;
        }
        __syncthreads();
#pragma unroll 8
        for (int kk = 0; kk < 32; ++kk) {
            float4 av0 = *reinterpret_cast<const float4*>(As + kk * 140 + ty * 8);
            float4 av1 = *reinterpret_cast<const float4*>(As + kk * 140 + ty * 8 + 4);
            float4 bv  = *reinterpret_cast<const float4*>(Bs + kk * 68 + tx * 4);
            float am[8] = {av0.x, av0.y, av0.z, av0.w, av1.x, av1.y, av1.z, av1.w};
            float bn[4] = {bv.x, bv.y, bv.z, bv.w};
#pragma unroll
            for (int i = 0; i < 8; ++i)
#pragma unroll
                for (int j = 0; j < 4; ++j) acc[i][j] = fmaf(am[i], bn[j], acc[i][j]);
        }
    }
#pragma unroll
    for (int i = 0; i < 8; ++i) {
        int row = m0 + ty * 8 + i;
        float4 o;
        o.x = acc[i][0] + bias4.x;
        o.y = acc[i][1] + bias4.y;
        o.z = acc[i][2] + bias4.z;
        o.w = acc[i][3] + bias4.w;
        *reinterpret_cast<float4*>(O + (size_t)row * 768 + n0 + tx * 4) = o;
    }
}

// ---------------------------------------------------------------------------
// Recurrence: grid = 48 (one WG per batch element), block = 768 (12 waves).
// Wave w (0..11) computes rows [w*64, w*64+64) of gh = W_hh . h each step.
// Threads 0..255 then do the per-column gate math, h update, and pd partials.
// Replicated scalar state (u, d, skip) per thread; pd combined via LDS -> all
// threads compute identical dns (same FP ops -> identical flags).
// ---------------------------------------------------------------------------
__global__ __launch_bounds__(768) void rec_layer(
    const float* __restrict__ GI, float* __restrict__ Yout,
    const float* __restrict__ whh, const float* __restrict__ bhh,
    const float* __restrict__ lwl, const float* __restrict__ lbl,
    const float* __restrict__ hid,
    float* __restrict__ hsout, float* __restrict__ tuout)
{
    __shared__ float hcur[256];
    __shared__ float gates[768];
    __shared__ float pdpart[4];

    const int tid  = threadIdx.x;
    const int lane = tid & 63;
    const int w    = tid >> 6;    // wave 0..11
    const int q    = lane >> 4;   // row-in-quad 0..3
    const int s    = lane & 15;   // k-sixteenth 0..15
    const int b    = blockIdx.x;

    // per-column constants + state (threads 0..255)
    float hreg = 0.f, lwc = 0.f, bhr = 0.f, bhz = 0.f, bhn = 0.f;
    if (tid < 256) {
        hreg = hid[tid];
        hcur[tid] = hreg;
        lwc = lwl[tid];
        bhr = bhh[tid]; bhz = bhh[256 + tid]; bhn = bhh[512 + tid];
    }
    const float lbv = lbl[0];
    __syncthreads();

    // W row-stream base for this lane: row (w*64 + q), k-offset s*4 floats
    const float* const Wbase = whh + ((size_t)(w * 64 + q)) * 256 + s * 4;

    float u = 1.f, d = 0.f;
    bool  skip = false;

    for (int t = 0; t < T_STEPS; ++t) {
        const size_t yrow = ((size_t)t * 48 + b) * 256;

        if (skip) {
            // u<0.5 -> bu=0 -> h, d unchanged; u = clip(u+d,0,1). No barriers.
            if (tid < 256) {
                Yout[yrow + tid] = hreg;
                if (t == T_STEPS - 1) hsout[b * 256 + tid] = hreg;
            }
            if (tid == 0) tuout[b * 768 + t] = 0.f;
            u = fminf(fmaxf(u + d, 0.f), 1.f);
            skip = (u < 0.5f);
            continue;
        }

        const float bu = rintf(u);  // RNE == jnp.round

        // prefetch gi for this step (consumed after barrier B1)
        float gir = 0.f, giz = 0.f, gin = 0.f;
        if (tid < 256) {
            const size_t gb = ((size_t)t * 48 + b) * 768;
            gir = GI[gb + tid]; giz = GI[gb + 256 + tid]; gin = GI[gb + 512 + tid];
        }

        // h fragment for k-slice s (float4 indices s, s+16, s+32, s+48)
        const float4 h0 = *reinterpret_cast<const float4*>(hcur + 4 * s);
        const float4 h1 = *reinterpret_cast<const float4*>(hcur + 4 * s + 64);
        const float4 h2 = *reinterpret_cast<const float4*>(hcur + 4 * s + 128);
        const float4 h3 = *reinterpret_cast<const float4*>(hcur + 4 * s + 192);

        // stream 64 rows of W through the wave: 4 rows per iter
        const float* Wp = Wbase;
#pragma unroll 4
        for (int it = 0; it < 16; ++it) {
            const float4 w0 = *reinterpret_cast<const float4*>(Wp);
            const float4 w1 = *reinterpret_cast<const float4*>(Wp + 64);
            const float4 w2 = *reinterpret_cast<const float4*>(Wp + 128);
            const float4 w3 = *reinterpret_cast<const float4*>(Wp + 192);
            float a;
            a = w0.x * h0.x;            a = fmaf(w0.y, h0.y, a);
            a = fmaf(w0.z, h0.z, a);    a = fmaf(w0.w, h0.w, a);
            a = fmaf(w1.x, h1.x, a);    a = fmaf(w1.y, h1.y, a);
            a = fmaf(w1.z, h1.z, a);    a = fmaf(w1.w, h1.w, a);
            a = fmaf(w2.x, h2.x, a);    a = fmaf(w2.y, h2.y, a);
            a = fmaf(w2.z, h2.z, a);    a = fmaf(w2.w, h2.w, a);
            a = fmaf(w3.x, h3.x, a);    a = fmaf(w3.y, h3.y, a);
            a = fmaf(w3.z, h3.z, a);    a = fmaf(w3.w, h3.w, a);
            // reduce over the 16 k-subs (offsets stay inside the 16-lane group)
            a += __shfl_xor(a, 1); a += __shfl_xor(a, 2);
            a += __shfl_xor(a, 4); a += __shfl_xor(a, 8);
            if (s == 0) gates[w * 64 + it * 4 + q] = a;
            Wp += 1024;  // advance 4 rows
        }

        __syncthreads();  // B1: gates complete; all hcur reads of this step done

        float pdv = 0.f;
        if (tid < 256) {
            const float ar = gates[tid];
            const float az = gates[256 + tid];
            const float an = gates[512 + tid];
            const float rr = sigm_(gir + ar + bhr);
            const float zz = sigm_(giz + az + bhz);
            const float nn = tanh_(gin + rr * (an + bhn));
            const float nh = ((1.f - zz) * nn + zz * hreg) * bu;
            hreg = nh;
            hcur[tid] = nh;
            Yout[yrow + tid] = nh;
            if (t == T_STEPS - 1) hsout[b * 256 + tid] = nh;
            pdv = nh * lwc;
        }
        // full-wave reduce (waves 0..3 carry data; others reduce zeros)
        pdv += __shfl_xor(pdv, 1);  pdv += __shfl_xor(pdv, 2);
        pdv += __shfl_xor(pdv, 4);  pdv += __shfl_xor(pdv, 8);
        pdv += __shfl_xor(pdv, 16); pdv += __shfl_xor(pdv, 32);
        if (lane == 0 && w < 4) pdpart[w] = pdv;
        if (tid == 0) tuout[b * 768 + t] = bu;

        __syncthreads();  // B2: hcur updated, pdpart ready

        const float dns = sigm_(((pdpart[0] + pdpart[1]) + (pdpart[2] + pdpart[3])) + lbv);
        u = dns * bu;
        d = dns;
        skip = (u < 0.5f);
    }
}

// ---------------------------------------------------------------------------
extern "C" void kernel_launch(void* const* d_in, const int* in_sizes, int n_in,
                              void* d_out, int out_size, void* d_ws, size_t ws_size,
                              hipStream_t stream)
{
    const float* x   = (const float*)d_in[0];  // (384,48,256)
    const float* hid = (const float*)d_in[1];  // (2,1,256)
    const float* wih = (const float*)d_in[2];  // (2,768,256)
    const float* whh = (const float*)d_in[3];  // (2,768,256)
    const float* bih = (const float*)d_in[4];  // (2,768)
    const float* bhh = (const float*)d_in[5];  // (2,768)
    const float* lw  = (const float*)d_in[6];  // (2,1,256)
    const float* lb  = (const float*)d_in[7];  // (2,1)
    float* out = (float*)d_out;

    float* ws = (float*)d_ws;
    float* GI = ws;                         // 18432*768
    float* Y0 = GI + (size_t)18432 * 768;   // 18432*256

    float* OUTy = out;                           // (384,48,256)
    float* HS   = out + (size_t)18432 * 256;     // (2,48,256)
    float* TU   = HS + 2 * 48 * 256;             // (48, 768): layer0 cols 0..383

    dim3 ggrid(12, 144), gblk(256);
    gemm_nt<<<ggrid, gblk, 0, stream>>>(x, wih, bih, GI);
    rec_layer<<<48, 768, 0, stream>>>(GI, Y0, whh, bhh, lw, lb, hid, HS, TU);
    gemm_nt<<<ggrid, gblk, 0, stream>>>(Y0, wih + 196608, bih + 768, GI);
    rec_layer<<<48, 768, 0, stream>>>(GI, OUTy, whh + 196608, bhh + 768,
                                      lw + 256, lb + 1, hid + 256,
                                      HS + 12288, TU + 384);
}